// Round 14
// baseline (88.410 us; speedup 1.0000x reference)
//
#include <hip/hip_runtime.h>

#define MPTS 1048576

typedef _Float16 f16;
typedef _Float16 f16x2 __attribute__((ext_vector_type(2)));
typedef _Float16 f16x4 __attribute__((ext_vector_type(4)));
typedef _Float16 f16x8 __attribute__((ext_vector_type(8)));
typedef float f32x4 __attribute__((ext_vector_type(4)));

// ---------------- workspace layout (bytes) ----------------
static const size_t OFF_Z    = 0;                          // float
static const size_t OFF_CNT  = 64;                         // int
static const size_t OFF_PL   = 256;                        // 3 planes HWC f32 (tier C only)
static const size_t OFF_PLD  = OFF_PL + 786432;            // 3 dup-pair planes f16: 786432 B
static const size_t OFF_W1H  = OFF_PLD + 786432;           // 8192 f16
static const size_t OFF_W2H  = OFF_W1H + 16384;            // 16384 f16
static const size_t OFF_BFLG = OFF_W2H + 32768;            // 1024 ints (lookback flags)
static const size_t OFF_LIST = OFF_BFLG + 4096;            // M ints
static const size_t OFF_PC   = OFF_LIST + (size_t)MPTS*4;  // M float4 (pre-scaled)
static const size_t WS_LIST  = OFF_PC;                     // tier C
static const size_t WS_PC    = OFF_PC + (size_t)MPTS*16;   // tier B (~22 MB) - main

__device__ __forceinline__ int iclamp(int v, int lo, int hi) {
    return v < lo ? lo : (v > hi ? hi : v);
}
__device__ __forceinline__ int imin(int a, int b) { return a < b ? a : b; }

__device__ __forceinline__ bool isact(float x, float y, float z) {
    float px = fmaf(x, 15.5f, 15.5f);
    float py = fmaf(y, 15.5f, 15.5f);
    float pz = fmaf(z, 15.5f, 15.5f);
    return (px > -1.0f) & (px < 32.0f) & (py > -1.0f) & (py < 32.0f) &
           (pz > -1.0f) & (pz < 32.0f);
}

// ---- bilinear setup: corner element-offsets (HWC, 64ch rows) + weights ----
struct Bi { int o00, o01, o10, o11; float w00, w01, w10, w11; };

__device__ __forceinline__ Bi mkbi(float pa, float pb) {
    float fa = floorf(pa), fb = floorf(pb);
    int ia0 = (int)fa, ib0 = (int)fb;
    int ia1 = ia0 + 1, ib1 = ib0 + 1;
    float wa1 = pa - fa, wa0 = 1.0f - wa1;
    float wb1 = pb - fb, wb0 = 1.0f - wb1;
    float va0 = (ia0 >= 0 && ia0 < 32) ? wa0 : 0.0f;
    float va1 = (ia1 >= 0 && ia1 < 32) ? wa1 : 0.0f;
    float vb0 = (ib0 >= 0 && ib0 < 32) ? wb0 : 0.0f;
    float vb1 = (ib1 >= 0 && ib1 < 32) ? wb1 : 0.0f;
    int ca0 = iclamp(ia0, 0, 31), ca1 = iclamp(ia1, 0, 31);
    int cb0 = iclamp(ib0, 0, 31), cb1 = iclamp(ib1, 0, 31);
    Bi r;
    r.o00 = (cb0 * 32 + ca0) * 64; r.o01 = (cb0 * 32 + ca1) * 64;
    r.o10 = (cb1 * 32 + ca0) * 64; r.o11 = (cb1 * 32 + ca1) * 64;
    r.w00 = va0 * vb0; r.w01 = va1 * vb0; r.w10 = va0 * vb1; r.w11 = va1 * vb1;
    return r;
}

// dot2-based bilinear of 4 channels from dup-pair plane.
__device__ __forceinline__ float4 lerp4d(const f16* __restrict__ base, const int4 P) {
    f16x8 r0 = *(const f16x8*)(base + P.x);
    f16x8 r1 = *(const f16x8*)(base + P.y);
    f16x2 w0 = __builtin_bit_cast(f16x2, P.z);
    f16x2 w1 = __builtin_bit_cast(f16x2, P.w);
    const f16x2* a0 = (const f16x2*)&r0;
    const f16x2* a1 = (const f16x2*)&r1;
    float4 r;
    r.x = __builtin_amdgcn_fdot2(a0[0], w0, __builtin_amdgcn_fdot2(a1[0], w1, 0.0f, false), false);
    r.y = __builtin_amdgcn_fdot2(a0[1], w0, __builtin_amdgcn_fdot2(a1[1], w1, 0.0f, false), false);
    r.z = __builtin_amdgcn_fdot2(a0[2], w0, __builtin_amdgcn_fdot2(a1[2], w1, 0.0f, false), false);
    r.w = __builtin_amdgcn_fdot2(a0[3], w0, __builtin_amdgcn_fdot2(a1[3], w1, 0.0f, false), false);
    return r;
}

// -------- bilinear sample of 16 channels (f32 planes; tier-C path) --------
__device__ __forceinline__ void samp16(const float* __restrict__ pl,
                                       float pa, float pb, int c0,
                                       float* __restrict__ f, const bool mult) {
    Bi B = mkbi(pa, pb);
    const float4* p00 = (const float4*)(pl + B.o00 + c0);
    const float4* p01 = (const float4*)(pl + B.o01 + c0);
    const float4* p10 = (const float4*)(pl + B.o10 + c0);
    const float4* p11 = (const float4*)(pl + B.o11 + c0);
#pragma unroll
    for (int q = 0; q < 4; ++q) {
        float4 g00 = p00[q], g01 = p01[q], g10 = p10[q], g11 = p11[q];
        float vx = fmaf(B.w00, g00.x, fmaf(B.w01, g01.x, fmaf(B.w10, g10.x, B.w11 * g11.x)));
        float vy = fmaf(B.w00, g00.y, fmaf(B.w01, g01.y, fmaf(B.w10, g10.y, B.w11 * g11.y)));
        float vz = fmaf(B.w00, g00.z, fmaf(B.w01, g01.z, fmaf(B.w10, g10.z, B.w11 * g11.z)));
        float vw = fmaf(B.w00, g00.w, fmaf(B.w01, g01.w, fmaf(B.w10, g10.w, B.w11 * g11.w)));
        if (mult) {
            f[4*q+0] *= vx; f[4*q+1] *= vy; f[4*q+2] *= vz; f[4*q+3] *= vw;
        } else {
            f[4*q+0] = vx; f[4*q+1] = vy; f[4*q+2] = vz; f[4*q+3] = vw;
        }
    }
}

// K1: dup-pair f16 planes (+ optional f32 HWC for tier C) + f16 weights;
// block 864: z=MLP(0).
__global__ void k_prep(const float* __restrict__ pxy, const float* __restrict__ pyz,
                       const float* __restrict__ pxz,
                       const float* __restrict__ w1, const float* __restrict__ w2,
                       const float* __restrict__ b1, const float* __restrict__ b2,
                       const float* __restrict__ w3, const float* __restrict__ b3,
                       float* __restrict__ planes, f16* __restrict__ dupl,
                       f16* __restrict__ w1h, f16* __restrict__ w2h,
                       float* __restrict__ zout, int wplanes) {
    if (blockIdx.x == 864) {
        int p = threadIdx.x;
        if (p >= 128) return;
        float h2p = b2[p];
        for (int o = 0; o < 128; ++o) h2p += w2[p * 128 + o] * fmaxf(b1[o], 0.0f);
        __shared__ float red[128];
        red[p] = fmaxf(h2p, 0.0f) * w3[p];
        __syncthreads();
        for (int s = 64; s > 0; s >>= 1) {
            if (p < s) red[p] += red[p + s];
            __syncthreads();
        }
        if (p == 0) *zout = red[0] + b3[0];
        return;
    }
    int tid = blockIdx.x * 256 + threadIdx.x;
    if (tid < 3 * 65536) {
        int t = tid >> 16;
        int r = tid & 65535;
        int hw = r >> 6;
        int c = r & 63;
        int y = hw >> 5, x = hw & 31;
        int xp1 = imin(x + 1, 31);
        const float* src = (t == 0) ? pxy : ((t == 1) ? pyz : pxz);
        float v  = src[c * 1024 + hw];
        float v1 = src[c * 1024 + y * 32 + xp1];
        if (wplanes) planes[tid] = v;
        f16* d = dupl + (size_t)t * 131072 + hw * 128 + c * 2;
        d[0] = (f16)v;
        d[1] = (f16)v1;
    } else if (tid < 3 * 65536 + 8192) {
        int r = tid - 3 * 65536;
        w1h[r] = (f16)w1[r];
    } else {
        int r = tid - (3 * 65536 + 8192);
        w2h[r] = (f16)w2[r];
    }
}

// K2: single-pass classify + decoupled-lookback prefix + scatter.
// 1024 blocks x 256 (all co-resident: 1024 < 2048-block HW capacity ->
// lookback spin is deadlock-free under any dispatch order). Device-scope
// atomics for cross-XCD flag visibility (G16). bflag pre-zeroed by memset.
template<bool PC>
__global__ void k_classify(const float* __restrict__ coords,
                           const float* __restrict__ zptr,
                           int* __restrict__ bflag, int* __restrict__ cnt,
                           int* __restrict__ list, float4* __restrict__ pc4,
                           float* __restrict__ out) {
    int t = threadIdx.x, bid = blockIdx.x, lane = t & 63, wv = t >> 6;
    const float4* c4 = (const float4*)coords + 768 * (size_t)bid + 3 * t;
    float4 a = c4[0], b = c4[1], c = c4[2];
    int base = bid * 1024 + t * 4;
    float xs[4] = {a.x, a.w, b.z, c.y};
    float ys[4] = {a.y, b.x, b.w, c.z};
    float zs[4] = {a.z, b.y, c.x, c.w};
    bool act[4];
#pragma unroll
    for (int j = 0; j < 4; ++j) act[j] = isact(xs[j], ys[j], zs[j]);
    int mine = (int)act[0] + (int)act[1] + (int)act[2] + (int)act[3];

    // wave inclusive scan
    int incl = mine;
#pragma unroll
    for (int off = 1; off <= 32; off <<= 1) {
        int v = __shfl_up(incl, off, 64);
        if (lane >= off) incl += v;
    }
    __shared__ int wtot[4];
    __shared__ int pw[4];
    if (lane == 63) wtot[wv] = incl;
    __syncthreads();
    int btot = wtot[0] + wtot[1] + wtot[2] + wtot[3];

    // publish this block's count (payload packed in the flag word: count+1)
    if (t == 0) atomicExch(&bflag[bid], btot + 1);

    // lookback: sum predecessors' published counts
    int pre = 0;
    for (int i = t; i < bid; i += 256) {
        int v;
        do { v = atomicAdd(&bflag[i], 0); } while (v == 0);
        pre += v - 1;
    }
#pragma unroll
    for (int off = 1; off <= 32; off <<= 1) pre += __shfl_xor(pre, off, 64);
    if (lane == 0) pw[wv] = pre;
    __syncthreads();
    int boffv = pw[0] + pw[1] + pw[2] + pw[3];

    if (bid == 1023 && t == 0) *cnt = boffv + btot;

    // inactive points -> z
    float z = *zptr;
#pragma unroll
    for (int j = 0; j < 4; ++j)
        if (!act[j]) out[base + j] = z;

    // scatter actives
    int wexcl = 0;
#pragma unroll
    for (int k = 0; k < 4; ++k) wexcl += (k < wv) ? wtot[k] : 0;
    int pos = boffv + wexcl + incl - mine;
#pragma unroll
    for (int j = 0; j < 4; ++j) {
        if (act[j]) {
            list[pos] = base + j;
            if (PC) {
                float4 p;
                p.x = fmaf(xs[j], 15.5f, 15.5f);
                p.y = fmaf(ys[j], 15.5f, 15.5f);
                p.z = fmaf(zs[j], 15.5f, 15.5f);
                p.w = 0.0f;
                pc4[pos] = p;
            }
            ++pos;
        }
    }
}

// K3 (tier B, MAIN): fused sample + MFMA MLP, one 64-pt tile per block.
// LDS lifetimes aliased: H1s overlays Fs, outp overlays BsP -> 19456 B.
__global__ __launch_bounds__(256, 2)
void k_fused(const float4* __restrict__ pc4, const f16* __restrict__ dupl,
             const f16* __restrict__ w1h, const f16* __restrict__ w2h,
             const float* __restrict__ b1, const float* __restrict__ b2,
             const float* __restrict__ w3, const float* __restrict__ b3,
             const int* __restrict__ cnt, const int* __restrict__ list,
             float* __restrict__ out) {
    const int n = *cnt;
    const int tile = blockIdx.x;
    if (tile * 64 >= n) return;

    __shared__ __attribute__((aligned(16))) char smem[16384 + 3072];
    f16*   Fs   = (f16*)smem;              // [pt][c] swizzled 128B rows; dies at af-load
    f16*   H1s  = (f16*)smem;              // [pt][neuron] swizzled 256B rows; born after
    int4*  BsP  = (int4*)(smem + 16384);   // 64x3; dies after sampling
    float* outp = (float*)(smem + 16384);  // [4][64]; born at epilogue

    const int t   = threadIdx.x;
    const int wv  = t >> 6;
    const int l   = t & 63;
    const int l15 = l & 15;
    const int lg  = l >> 4;
    const int ptw = t >> 4;
    const int cq  = t & 15;

    const float b3v = b3[0];

    // ---------- phase 0: dot2 bilinear setup, once per (point, plane) ----------
    if ((t & 3) < 3) {
        int pt0 = t >> 2;
        int pl  = t & 3;
        int ic = imin(tile * 64 + pt0, n - 1);
        float4 c = pc4[ic];
        float pa = (pl == 1) ? c.y : c.x;
        float pb = (pl == 0) ? c.y : c.z;
        float fa = floorf(pa), fb = floorf(pb);
        int ia0 = (int)fa, ib0 = (int)fb;
        float wa1 = pa - fa, wa0 = 1.0f - wa1;
        float wb1 = pb - fb, wb0 = 1.0f - wb1;
        float va0 = (ia0 >= 0 && ia0 < 32) ? wa0 : 0.0f;
        float va1 = (ia0 + 1 >= 0 && ia0 + 1 < 32) ? wa1 : 0.0f;
        float vb0 = (ib0 >= 0 && ib0 < 32) ? wb0 : 0.0f;
        float vb1 = (ib0 + 1 >= 0 && ib0 + 1 < 32) ? wb1 : 0.0f;
        int xb = iclamp(ia0, 0, 31);
        float wx0 = (ia0 < 0) ? va1 : va0;
        float wx1 = (ia0 < 0) ? 0.0f : va1;
        int yb0 = iclamp(ib0, 0, 31), yb1 = iclamp(ib0 + 1, 0, 31);
        f16x2 p0; p0[0] = (f16)(wx0 * vb0); p0[1] = (f16)(wx1 * vb0);
        f16x2 p1; p1[0] = (f16)(wx0 * vb1); p1[1] = (f16)(wx1 * vb1);
        int o0 = (yb0 * 32 + xb) * 128;
        int o1 = (yb1 * 32 + xb) * 128;
        BsP[pt0 * 3 + pl] = make_int4(o0, o1,
                                      __builtin_bit_cast(int, p0),
                                      __builtin_bit_cast(int, p1));
    }
    __syncthreads();

    // ---------- sampling into Fs: 4 passes x 16 points, dot2 gathers ----------
    const f16* bch = dupl + cq * 8;
#pragma unroll
    for (int pass = 0; pass < 4; ++pass) {
        int pt = pass * 16 + ptw;
        float4 s0 = lerp4d(bch,          BsP[pt * 3 + 0]);
        float4 s1 = lerp4d(bch + 131072, BsP[pt * 3 + 1]);
        float4 s2 = lerp4d(bch + 262144, BsP[pt * 3 + 2]);
        float4 f;
        f.x = (s0.x * s1.x) * s2.x;
        f.y = (s0.y * s1.y) * s2.y;
        f.z = (s0.z * s1.z) * s2.z;
        f.w = (s0.w * s1.w) * s2.w;
        f16x4 pk;
        pk[0] = (f16)f.x; pk[1] = (f16)f.y; pk[2] = (f16)f.z; pk[3] = (f16)f.w;
        *(f16x4*)((char*)Fs + pt * 128 + ((cq * 8) ^ ((pt & 7) << 4))) = pk;
    }
    __syncthreads();   // Fs ready (and all BsP reads done)

    // ---------- B-frags (features) from Fs ----------
    f16x8 af[4][2];
#pragma unroll
    for (int Mt = 0; Mt < 4; ++Mt) {
        int row = Mt * 16 + l15;
        const char* rb = (const char*)Fs + row * 128;
        int sw = (row & 7) << 4;
        af[Mt][0] = *(const f16x8*)(rb + ((lg * 16) ^ sw));
        af[Mt][1] = *(const f16x8*)(rb + ((64 + lg * 16) ^ sw));
    }

    // ---------- A-frags (weights) + per-lane bias/w3 quads (L1-hot) ----------
    f16x8 wf1[2][2];
    f16x8 wf2[2][4];
    f32x4 b1q[2], b2q[2], w3q[2];
#pragma unroll
    for (int ntl = 0; ntl < 2; ++ntl) {
        int nrow = (wv * 2 + ntl) * 16 + l15;
        wf1[ntl][0] = *(const f16x8*)(w1h + nrow * 64 + lg * 8);
        wf1[ntl][1] = *(const f16x8*)(w1h + nrow * 64 + 32 + lg * 8);
#pragma unroll
        for (int ks = 0; ks < 4; ++ks)
            wf2[ntl][ks] = *(const f16x8*)(w2h + nrow * 128 + ks * 32 + lg * 8);
        int nb = (wv * 2 + ntl) * 16 + lg * 4;
        b1q[ntl] = *(const f32x4*)(b1 + nb);
        b2q[ntl] = *(const f32x4*)(b2 + nb);
        w3q[ntl] = *(const f32x4*)(w3 + nb);
    }
    __syncthreads();   // all waves done reading Fs -> H1s may overwrite

    // ---------- layer 1: C1[neuron][pt] ----------
    f32x4 acc[2][4];
#pragma unroll
    for (int ntl = 0; ntl < 2; ++ntl)
#pragma unroll
        for (int Mt = 0; Mt < 4; ++Mt) acc[ntl][Mt] = b1q[ntl];
    __builtin_amdgcn_s_setprio(1);
#pragma unroll
    for (int Mt = 0; Mt < 4; ++Mt) {
#pragma unroll
        for (int ntl = 0; ntl < 2; ++ntl) {
            acc[ntl][Mt] = __builtin_amdgcn_mfma_f32_16x16x32_f16(wf1[ntl][0], af[Mt][0], acc[ntl][Mt], 0, 0, 0);
            acc[ntl][Mt] = __builtin_amdgcn_mfma_f32_16x16x32_f16(wf1[ntl][1], af[Mt][1], acc[ntl][Mt], 0, 0, 0);
        }
    }
    __builtin_amdgcn_s_setprio(0);

    // ---------- H1 -> LDS (overlays Fs) ----------
#pragma unroll
    for (int ntl = 0; ntl < 2; ++ntl) {
#pragma unroll
        for (int Mt = 0; Mt < 4; ++Mt) {
            int pt = Mt * 16 + l15;
            int off = (((wv * 2 + ntl) * 32 + lg * 8) ^ ((pt & 7) << 4));
            f16x4 h;
            h[0] = (f16)fmaxf(acc[ntl][Mt][0], 0.0f);
            h[1] = (f16)fmaxf(acc[ntl][Mt][1], 0.0f);
            h[2] = (f16)fmaxf(acc[ntl][Mt][2], 0.0f);
            h[3] = (f16)fmaxf(acc[ntl][Mt][3], 0.0f);
            *(f16x4*)((char*)H1s + pt * 256 + off) = h;
        }
    }
    __syncthreads();   // H1s ready

    // ---------- layer 2: C2[neuron][pt] ----------
    f32x4 acc2[2][4];
#pragma unroll
    for (int ntl = 0; ntl < 2; ++ntl)
#pragma unroll
        for (int Mt = 0; Mt < 4; ++Mt) acc2[ntl][Mt] = b2q[ntl];
#pragma unroll
    for (int Mt = 0; Mt < 4; ++Mt) {
        int row = Mt * 16 + l15;
        const char* rb = (const char*)H1s + row * 256;
        int sw = (row & 7) << 4;
        f16x8 a0 = *(const f16x8*)(rb + ((lg * 16) ^ sw));
        f16x8 a1 = *(const f16x8*)(rb + ((64 + lg * 16) ^ sw));
        f16x8 a2 = *(const f16x8*)(rb + ((128 + lg * 16) ^ sw));
        f16x8 a3 = *(const f16x8*)(rb + ((192 + lg * 16) ^ sw));
        __builtin_amdgcn_s_setprio(1);
#pragma unroll
        for (int ntl = 0; ntl < 2; ++ntl) {
            acc2[ntl][Mt] = __builtin_amdgcn_mfma_f32_16x16x32_f16(wf2[ntl][0], a0, acc2[ntl][Mt], 0, 0, 0);
            acc2[ntl][Mt] = __builtin_amdgcn_mfma_f32_16x16x32_f16(wf2[ntl][1], a1, acc2[ntl][Mt], 0, 0, 0);
            acc2[ntl][Mt] = __builtin_amdgcn_mfma_f32_16x16x32_f16(wf2[ntl][2], a2, acc2[ntl][Mt], 0, 0, 0);
            acc2[ntl][Mt] = __builtin_amdgcn_mfma_f32_16x16x32_f16(wf2[ntl][3], a3, acc2[ntl][Mt], 0, 0, 0);
        }
        __builtin_amdgcn_s_setprio(0);
    }

    // ---------- layer 3: lane-local over 8 neurons + 2 shuffles ----------
#pragma unroll
    for (int Mt = 0; Mt < 4; ++Mt) {
        float s = 0.0f;
#pragma unroll
        for (int ntl = 0; ntl < 2; ++ntl)
#pragma unroll
            for (int r = 0; r < 4; ++r)
                s = fmaf(fmaxf(acc2[ntl][Mt][r], 0.0f), w3q[ntl][r], s);
        s += __shfl_xor(s, 16, 64);
        s += __shfl_xor(s, 32, 64);
        if (lg == 0) outp[wv * 64 + Mt * 16 + l15] = s;
    }
    __syncthreads();   // outp ready
    if (t < 64) {
        int gi = tile * 64 + t;
        if (gi < n) {
            float s = outp[0 * 64 + t] + outp[1 * 64 + t] +
                      outp[2 * 64 + t] + outp[3 * 64 + t] + b3v;
            out[list[gi]] = s;
        }
    }
}

// K3 (tier C): fused via list, f32 planes. 16384 x 256.
__global__ __launch_bounds__(256, 2)
void k_mlp(const float* __restrict__ coords, const float* __restrict__ planes,
           const f16* __restrict__ w1h, const f16* __restrict__ w2h,
           const float* __restrict__ b1, const float* __restrict__ b2,
           const float* __restrict__ w3, const float* __restrict__ b3,
           const int* __restrict__ cnt, const int* __restrict__ list,
           float* __restrict__ out) {
    const int n = *cnt;
    const int tile = blockIdx.x;
    if (tile * 64 >= n) return;

    __shared__ __attribute__((aligned(16))) f16 Fs[64 * 64];
    __shared__ __attribute__((aligned(16))) f16 H1s[64 * 128];
    __shared__ float outp[4][64];

    const int t   = threadIdx.x;
    const int wv  = t >> 6;
    const int l   = t & 63;
    const int l15 = l & 15;
    const int lg  = l >> 4;

    const float* pl0 = planes;
    const float* pl1 = planes + 65536;
    const float* pl2 = planes + 131072;

    f16x8 wf1[2][2];
    f16x8 wf2[2][4];
    float b1v[2], b2v[2], w3v[2];
#pragma unroll
    for (int ntl = 0; ntl < 2; ++ntl) {
        int nrow = (wv * 2 + ntl) * 16 + l15;
#pragma unroll
        for (int ks = 0; ks < 2; ++ks)
            wf1[ntl][ks] = *(const f16x8*)(w1h + nrow * 64 + ks * 32 + lg * 8);
#pragma unroll
        for (int ks = 0; ks < 4; ++ks)
            wf2[ntl][ks] = *(const f16x8*)(w2h + nrow * 128 + ks * 32 + lg * 8);
        b1v[ntl] = b1[nrow];
        b2v[ntl] = b2[nrow];
        w3v[ntl] = w3[nrow];
    }
    const float b3v = b3[0];

    {
        int pt = t >> 2, c0 = (t & 3) * 16;
        int ic = imin(tile * 64 + pt, n - 1);
        int i = list[ic];
        float px = fmaf(coords[3 * i + 0], 15.5f, 15.5f);
        float py = fmaf(coords[3 * i + 1], 15.5f, 15.5f);
        float pz = fmaf(coords[3 * i + 2], 15.5f, 15.5f);
        float feat[16];
        samp16(pl0, px, py, c0, feat, false);
        samp16(pl1, py, pz, c0, feat, true);
        samp16(pl2, px, pz, c0, feat, true);
        int sw = (pt & 7) << 4;
        char* Fb = (char*)Fs + pt * 128;
        f16x8 pk;
#pragma unroll
        for (int j = 0; j < 8; ++j) pk[j] = (f16)feat[j];
        *(f16x8*)(Fb + ((c0 * 2) ^ sw)) = pk;
#pragma unroll
        for (int j = 0; j < 8; ++j) pk[j] = (f16)feat[8 + j];
        *(f16x8*)(Fb + ((c0 * 2 + 16) ^ sw)) = pk;
    }
    __syncthreads();

    f32x4 acc[2][4];
#pragma unroll
    for (int ntl = 0; ntl < 2; ++ntl) {
        f32x4 ini = {b1v[ntl], b1v[ntl], b1v[ntl], b1v[ntl]};
#pragma unroll
        for (int Mt = 0; Mt < 4; ++Mt) acc[ntl][Mt] = ini;
    }
#pragma unroll
    for (int Mt = 0; Mt < 4; ++Mt) {
        int row = Mt * 16 + l15;
        const char* rb = (const char*)Fs + row * 128;
        int sw = (row & 7) << 4;
        f16x8 a0 = *(const f16x8*)(rb + ((lg * 16) ^ sw));
        f16x8 a1 = *(const f16x8*)(rb + ((64 + lg * 16) ^ sw));
#pragma unroll
        for (int ntl = 0; ntl < 2; ++ntl) {
            acc[ntl][Mt] = __builtin_amdgcn_mfma_f32_16x16x32_f16(a0, wf1[ntl][0], acc[ntl][Mt], 0, 0, 0);
            acc[ntl][Mt] = __builtin_amdgcn_mfma_f32_16x16x32_f16(a1, wf1[ntl][1], acc[ntl][Mt], 0, 0, 0);
        }
    }
#pragma unroll
    for (int ntl = 0; ntl < 2; ++ntl) {
        int ncol = (wv * 2 + ntl) * 16 + l15;
#pragma unroll
        for (int Mt = 0; Mt < 4; ++Mt) {
#pragma unroll
            for (int r = 0; r < 4; ++r) {
                int prow = Mt * 16 + lg * 4 + r;
                float v = fmaxf(acc[ntl][Mt][r], 0.0f);
                *(f16*)((char*)H1s + prow * 256 + ((ncol * 2) ^ ((prow & 7) << 4))) = (f16)v;
            }
        }
    }
    __syncthreads();

    f32x4 acc2[2][4];
#pragma unroll
    for (int ntl = 0; ntl < 2; ++ntl) {
        f32x4 ini = {b2v[ntl], b2v[ntl], b2v[ntl], b2v[ntl]};
#pragma unroll
        for (int Mt = 0; Mt < 4; ++Mt) acc2[ntl][Mt] = ini;
    }
#pragma unroll
    for (int Mt = 0; Mt < 4; ++Mt) {
        int row = Mt * 16 + l15;
        const char* rb = (const char*)H1s + row * 256;
        int sw = (row & 7) << 4;
        f16x8 a0 = *(const f16x8*)(rb + ((lg * 16) ^ sw));
        f16x8 a1 = *(const f16x8*)(rb + ((64 + lg * 16) ^ sw));
        f16x8 a2 = *(const f16x8*)(rb + ((128 + lg * 16) ^ sw));
        f16x8 a3 = *(const f16x8*)(rb + ((192 + lg * 16) ^ sw));
#pragma unroll
        for (int ntl = 0; ntl < 2; ++ntl) {
            acc2[ntl][Mt] = __builtin_amdgcn_mfma_f32_16x16x32_f16(a0, wf2[ntl][0], acc2[ntl][Mt], 0, 0, 0);
            acc2[ntl][Mt] = __builtin_amdgcn_mfma_f32_16x16x32_f16(a1, wf2[ntl][1], acc2[ntl][Mt], 0, 0, 0);
            acc2[ntl][Mt] = __builtin_amdgcn_mfma_f32_16x16x32_f16(a2, wf2[ntl][2], acc2[ntl][Mt], 0, 0, 0);
            acc2[ntl][Mt] = __builtin_amdgcn_mfma_f32_16x16x32_f16(a3, wf2[ntl][3], acc2[ntl][Mt], 0, 0, 0);
        }
    }

    float part[4][4];
#pragma unroll
    for (int Mt = 0; Mt < 4; ++Mt)
#pragma unroll
        for (int r = 0; r < 4; ++r)
            part[Mt][r] = fmaxf(acc2[0][Mt][r], 0.0f) * w3v[0] +
                          fmaxf(acc2[1][Mt][r], 0.0f) * w3v[1];
#pragma unroll
    for (int off = 1; off <= 8; off <<= 1) {
#pragma unroll
        for (int Mt = 0; Mt < 4; ++Mt)
#pragma unroll
            for (int r = 0; r < 4; ++r)
                part[Mt][r] += __shfl_xor(part[Mt][r], off, 64);
    }
    if (l15 == 0) {
#pragma unroll
        for (int Mt = 0; Mt < 4; ++Mt)
#pragma unroll
            for (int r = 0; r < 4; ++r)
                outp[wv][Mt * 16 + lg * 4 + r] = part[Mt][r];
    }
    __syncthreads();
    if (t < 64) {
        int gi = tile * 64 + t;
        if (gi < n) {
            float s = outp[0][t] + outp[1][t] + outp[2][t] + outp[3][t] + b3v;
            out[list[gi]] = s;
        }
    }
}

// Fallback (no workspace): per-thread f32 MLP over all points.
__global__ void k_fallback(const float* __restrict__ coords,
                           const float* __restrict__ p0, const float* __restrict__ p1,
                           const float* __restrict__ p2,
                           const float* __restrict__ w1, const float* __restrict__ b1,
                           const float* __restrict__ w2, const float* __restrict__ b2,
                           const float* __restrict__ w3, const float* __restrict__ b3,
                           float* __restrict__ out) {
    int i = blockIdx.x * 256 + threadIdx.x;
    if (i >= MPTS) return;
    float x = coords[3 * i + 0], y = coords[3 * i + 1], z = coords[3 * i + 2];
    float px = fmaf(x, 15.5f, 15.5f);
    float py = fmaf(y, 15.5f, 15.5f);
    float pz = fmaf(z, 15.5f, 15.5f);
    float feat[64];
    const float* pls[3] = {p0, p1, p2};
    float pa[3] = {px, py, px}, pb[3] = {py, pz, pz};
    for (int pidx = 0; pidx < 3; ++pidx) {
        float paf = pa[pidx], pbf = pb[pidx];
        float fa = floorf(paf), fb = floorf(pbf);
        int ia0 = (int)fa, ib0 = (int)fb, ia1 = ia0 + 1, ib1 = ib0 + 1;
        float wa1 = paf - fa, wa0 = 1.0f - wa1, wb1 = pbf - fb, wb0 = 1.0f - wb1;
        float va0 = (ia0 >= 0 && ia0 < 32) ? wa0 : 0.0f;
        float va1 = (ia1 >= 0 && ia1 < 32) ? wa1 : 0.0f;
        float vb0 = (ib0 >= 0 && ib0 < 32) ? wb0 : 0.0f;
        float vb1 = (ib1 >= 0 && ib1 < 32) ? wb1 : 0.0f;
        int ca0 = iclamp(ia0, 0, 31), ca1 = iclamp(ia1, 0, 31);
        int cb0 = iclamp(ib0, 0, 31), cb1 = iclamp(ib1, 0, 31);
        float w00 = va0 * vb0, w01 = va1 * vb0, w10 = va0 * vb1, w11 = va1 * vb1;
        int o00 = cb0 * 32 + ca0, o01 = cb0 * 32 + ca1;
        int o10 = cb1 * 32 + ca0, o11 = cb1 * 32 + ca1;
        const float* pl = pls[pidx];
        for (int c = 0; c < 64; ++c) {
            const float* pc = pl + c * 1024;
            float v = fmaf(w00, pc[o00], fmaf(w01, pc[o01],
                      fmaf(w10, pc[o10], w11 * pc[o11])));
            if (pidx == 0) feat[c] = v; else feat[c] *= v;
        }
    }
    float oa = b3[0];
    for (int half = 0; half < 2; ++half) {
        float h2h[64];
        for (int p = 0; p < 64; ++p) h2h[p] = b2[half * 64 + p];
        for (int o = 0; o < 128; ++o) {
            float a = b1[o];
            for (int c = 0; c < 64; ++c) a = fmaf(feat[c], w1[o * 64 + c], a);
            float r = fmaxf(a, 0.0f);
            for (int p = 0; p < 64; ++p) h2h[p] = fmaf(r, w2[(half * 64 + p) * 128 + o], h2h[p]);
        }
        for (int p = 0; p < 64; ++p) oa = fmaf(fmaxf(h2h[p], 0.0f), w3[half * 64 + p], oa);
    }
    out[i] = oa;
}

extern "C" void kernel_launch(void* const* d_in, const int* in_sizes, int n_in,
                              void* d_out, int out_size, void* d_ws, size_t ws_size,
                              hipStream_t stream) {
    const float* coords = (const float*)d_in[0];
    const float* pxy    = (const float*)d_in[1];
    const float* pyz    = (const float*)d_in[2];
    const float* pxz    = (const float*)d_in[3];
    const float* w1     = (const float*)d_in[4];
    const float* b1     = (const float*)d_in[5];
    const float* w2     = (const float*)d_in[6];
    const float* b2     = (const float*)d_in[7];
    const float* w3     = (const float*)d_in[8];
    const float* b3     = (const float*)d_in[9];
    float* out = (float*)d_out;

    if (ws_size >= WS_LIST) {
        float*  zout   = (float*)((char*)d_ws + OFF_Z);
        int*    cnt    = (int*)((char*)d_ws + OFF_CNT);
        float*  planes = (float*)((char*)d_ws + OFF_PL);
        f16*    dupl   = (f16*)((char*)d_ws + OFF_PLD);
        f16*    w1h    = (f16*)((char*)d_ws + OFF_W1H);
        f16*    w2h    = (f16*)((char*)d_ws + OFF_W2H);
        int*    bflag  = (int*)((char*)d_ws + OFF_BFLG);
        int*    list   = (int*)((char*)d_ws + OFF_LIST);
        float4* pc4    = (float4*)((char*)d_ws + OFF_PC);
        const bool pc  = (ws_size >= WS_PC);

        hipMemsetAsync(bflag, 0, 4096, stream);
        k_prep<<<865, 256, 0, stream>>>(pxy, pyz, pxz, w1, w2, b1, b2, w3, b3,
                                        planes, dupl, w1h, w2h, zout, pc ? 0 : 1);
        if (pc) {
            k_classify<true><<<1024, 256, 0, stream>>>(coords, zout, bflag, cnt,
                                                       list, pc4, out);
            k_fused<<<16384, 256, 0, stream>>>(pc4, dupl, w1h, w2h,
                                               b1, b2, w3, b3, cnt, list, out);
        } else {
            k_classify<false><<<1024, 256, 0, stream>>>(coords, zout, bflag, cnt,
                                                        list, nullptr, out);
            k_mlp<<<16384, 256, 0, stream>>>(coords, planes, w1h, w2h,
                                             b1, b2, w3, b3, cnt, list, out);
        }
    } else {
        k_fallback<<<4096, 256, 0, stream>>>(coords, pxy, pyz, pxz,
                                             w1, b1, w2, b2, w3, b3, out);
    }
}

// Round 15
// 83.739 us; speedup vs baseline: 1.0558x; 1.0558x over previous
//
#include <hip/hip_runtime.h>

#define MPTS 1048576

typedef _Float16 f16;
typedef _Float16 f16x2 __attribute__((ext_vector_type(2)));
typedef _Float16 f16x4 __attribute__((ext_vector_type(4)));
typedef _Float16 f16x8 __attribute__((ext_vector_type(8)));
typedef float f32x4 __attribute__((ext_vector_type(4)));

// ---------------- workspace layout (bytes) ----------------
static const size_t OFF_Z    = 0;                          // float
static const size_t OFF_CNT  = 64;                         // int
static const size_t OFF_PL   = 256;                        // 3 planes HWC f32 (tier C only)
static const size_t OFF_PLD  = OFF_PL + 786432;            // 3 dup-pair planes f16: 786432 B
static const size_t OFF_W1H  = OFF_PLD + 786432;           // 8192 f16
static const size_t OFF_W2H  = OFF_W1H + 16384;            // 16384 f16
static const size_t OFF_BCNT = OFF_W2H + 32768;            // 1024 ints
static const size_t OFF_BOFF = OFF_BCNT + 4096;            // 1024 ints
static const size_t OFF_LIST = OFF_BOFF + 4096;            // M ints
static const size_t OFF_PC   = OFF_LIST + (size_t)MPTS*4;  // M float4 (pre-scaled)
static const size_t WS_LIST  = OFF_PC;                     // tier C
static const size_t WS_PC    = OFF_PC + (size_t)MPTS*16;   // tier B (~22 MB) - main

__device__ __forceinline__ int iclamp(int v, int lo, int hi) {
    return v < lo ? lo : (v > hi ? hi : v);
}
__device__ __forceinline__ int imin(int a, int b) { return a < b ? a : b; }

__device__ __forceinline__ bool isact(float x, float y, float z) {
    float px = fmaf(x, 15.5f, 15.5f);
    float py = fmaf(y, 15.5f, 15.5f);
    float pz = fmaf(z, 15.5f, 15.5f);
    return (px > -1.0f) & (px < 32.0f) & (py > -1.0f) & (py < 32.0f) &
           (pz > -1.0f) & (pz < 32.0f);
}

// ---- bilinear setup: corner element-offsets (HWC, 64ch rows) + weights ----
struct Bi { int o00, o01, o10, o11; float w00, w01, w10, w11; };

__device__ __forceinline__ Bi mkbi(float pa, float pb) {
    float fa = floorf(pa), fb = floorf(pb);
    int ia0 = (int)fa, ib0 = (int)fb;
    int ia1 = ia0 + 1, ib1 = ib0 + 1;
    float wa1 = pa - fa, wa0 = 1.0f - wa1;
    float wb1 = pb - fb, wb0 = 1.0f - wb1;
    float va0 = (ia0 >= 0 && ia0 < 32) ? wa0 : 0.0f;
    float va1 = (ia1 >= 0 && ia1 < 32) ? wa1 : 0.0f;
    float vb0 = (ib0 >= 0 && ib0 < 32) ? wb0 : 0.0f;
    float vb1 = (ib1 >= 0 && ib1 < 32) ? wb1 : 0.0f;
    int ca0 = iclamp(ia0, 0, 31), ca1 = iclamp(ia1, 0, 31);
    int cb0 = iclamp(ib0, 0, 31), cb1 = iclamp(ib1, 0, 31);
    Bi r;
    r.o00 = (cb0 * 32 + ca0) * 64; r.o01 = (cb0 * 32 + ca1) * 64;
    r.o10 = (cb1 * 32 + ca0) * 64; r.o11 = (cb1 * 32 + ca1) * 64;
    r.w00 = va0 * vb0; r.w01 = va1 * vb0; r.w10 = va0 * vb1; r.w11 = va1 * vb1;
    return r;
}

// dot2 reduce of pre-loaded pair rows (compute half of lerp4d).
__device__ __forceinline__ float4 dot4p(f16x8 r0, f16x8 r1, int wz, int ww) {
    f16x2 w0 = __builtin_bit_cast(f16x2, wz);
    f16x2 w1 = __builtin_bit_cast(f16x2, ww);
    const f16x2* a0 = (const f16x2*)&r0;
    const f16x2* a1 = (const f16x2*)&r1;
    float4 r;
    r.x = __builtin_amdgcn_fdot2(a0[0], w0, __builtin_amdgcn_fdot2(a1[0], w1, 0.0f, false), false);
    r.y = __builtin_amdgcn_fdot2(a0[1], w0, __builtin_amdgcn_fdot2(a1[1], w1, 0.0f, false), false);
    r.z = __builtin_amdgcn_fdot2(a0[2], w0, __builtin_amdgcn_fdot2(a1[2], w1, 0.0f, false), false);
    r.w = __builtin_amdgcn_fdot2(a0[3], w0, __builtin_amdgcn_fdot2(a1[3], w1, 0.0f, false), false);
    return r;
}

// -------- bilinear sample of 16 channels (f32 planes; tier-C path) --------
__device__ __forceinline__ void samp16(const float* __restrict__ pl,
                                       float pa, float pb, int c0,
                                       float* __restrict__ f, const bool mult) {
    Bi B = mkbi(pa, pb);
    const float4* p00 = (const float4*)(pl + B.o00 + c0);
    const float4* p01 = (const float4*)(pl + B.o01 + c0);
    const float4* p10 = (const float4*)(pl + B.o10 + c0);
    const float4* p11 = (const float4*)(pl + B.o11 + c0);
#pragma unroll
    for (int q = 0; q < 4; ++q) {
        float4 g00 = p00[q], g01 = p01[q], g10 = p10[q], g11 = p11[q];
        float vx = fmaf(B.w00, g00.x, fmaf(B.w01, g01.x, fmaf(B.w10, g10.x, B.w11 * g11.x)));
        float vy = fmaf(B.w00, g00.y, fmaf(B.w01, g01.y, fmaf(B.w10, g10.y, B.w11 * g11.y)));
        float vz = fmaf(B.w00, g00.z, fmaf(B.w01, g01.z, fmaf(B.w10, g10.z, B.w11 * g11.z)));
        float vw = fmaf(B.w00, g00.w, fmaf(B.w01, g01.w, fmaf(B.w10, g10.w, B.w11 * g11.w)));
        if (mult) {
            f[4*q+0] *= vx; f[4*q+1] *= vy; f[4*q+2] *= vz; f[4*q+3] *= vw;
        } else {
            f[4*q+0] = vx; f[4*q+1] = vy; f[4*q+2] = vz; f[4*q+3] = vw;
        }
    }
}

// K1: dup-pair f16 planes (+ optional f32 HWC for tier C) + f16 weights;
// block 864: z=MLP(0).
__global__ void k_prep(const float* __restrict__ pxy, const float* __restrict__ pyz,
                       const float* __restrict__ pxz,
                       const float* __restrict__ w1, const float* __restrict__ w2,
                       const float* __restrict__ b1, const float* __restrict__ b2,
                       const float* __restrict__ w3, const float* __restrict__ b3,
                       float* __restrict__ planes, f16* __restrict__ dupl,
                       f16* __restrict__ w1h, f16* __restrict__ w2h,
                       float* __restrict__ zout, int wplanes) {
    if (blockIdx.x == 864) {
        int p = threadIdx.x;
        if (p >= 128) return;
        float h2p = b2[p];
        for (int o = 0; o < 128; ++o) h2p += w2[p * 128 + o] * fmaxf(b1[o], 0.0f);
        __shared__ float red[128];
        red[p] = fmaxf(h2p, 0.0f) * w3[p];
        __syncthreads();
        for (int s = 64; s > 0; s >>= 1) {
            if (p < s) red[p] += red[p + s];
            __syncthreads();
        }
        if (p == 0) *zout = red[0] + b3[0];
        return;
    }
    int tid = blockIdx.x * 256 + threadIdx.x;
    if (tid < 3 * 65536) {
        int t = tid >> 16;
        int r = tid & 65535;
        int hw = r >> 6;
        int c = r & 63;
        int y = hw >> 5, x = hw & 31;
        int xp1 = imin(x + 1, 31);
        const float* src = (t == 0) ? pxy : ((t == 1) ? pyz : pxz);
        float v  = src[c * 1024 + hw];
        float v1 = src[c * 1024 + y * 32 + xp1];
        if (wplanes) planes[tid] = v;
        f16* d = dupl + (size_t)t * 131072 + hw * 128 + c * 2;
        d[0] = (f16)v;
        d[1] = (f16)v1;
    } else if (tid < 3 * 65536 + 8192) {
        int r = tid - 3 * 65536;
        w1h[r] = (f16)w1[r];
    } else {
        int r = tid - (3 * 65536 + 8192);
        w2h[r] = (f16)w2[r];
    }
}

// K2a: per-block active counts; inactive points get out = z. 1024 x 256.
__global__ void k_count(const float* __restrict__ coords, const float* __restrict__ zptr,
                        int* __restrict__ bcnt, float* __restrict__ out) {
    int t = threadIdx.x, bid = blockIdx.x;
    const float4* c4 = (const float4*)coords + 768 * (size_t)bid + 3 * t;
    float4 a = c4[0], b = c4[1], c = c4[2];
    int base = bid * 1024 + t * 4;
    float z = *zptr;
    bool a0 = isact(a.x, a.y, a.z);
    bool a1 = isact(a.w, b.x, b.y);
    bool a2 = isact(b.z, b.w, c.x);
    bool a3 = isact(c.y, c.z, c.w);
    if (!a0) out[base + 0] = z;
    if (!a1) out[base + 1] = z;
    if (!a2) out[base + 2] = z;
    if (!a3) out[base + 3] = z;
    int s = (int)a0 + (int)a1 + (int)a2 + (int)a3;
#pragma unroll
    for (int off = 1; off <= 32; off <<= 1) s += __shfl_xor(s, off, 64);
    __shared__ int wt[4];
    if ((t & 63) == 0) wt[t >> 6] = s;
    __syncthreads();
    if (t == 0) bcnt[bid] = wt[0] + wt[1] + wt[2] + wt[3];
}

// K2b: exclusive scan of 1024 block counts. 1 x 1024.
__global__ void k_scan(const int* __restrict__ bcnt, int* __restrict__ boff,
                       int* __restrict__ cnt) {
    int t = threadIdx.x, lane = t & 63, wv = t >> 6;
    int mine = bcnt[t];
    int incl = mine;
#pragma unroll
    for (int off = 1; off <= 32; off <<= 1) {
        int v = __shfl_up(incl, off, 64);
        if (lane >= off) incl += v;
    }
    __shared__ int wtot[16];
    if (lane == 63) wtot[wv] = incl;
    __syncthreads();
    int wexcl = 0;
#pragma unroll
    for (int k = 0; k < 16; ++k) wexcl += (k < wv) ? wtot[k] : 0;
    boff[t] = wexcl + incl - mine;
    if (t == 1023) *cnt = wexcl + incl;
}

// K2c: scatter active indices (+ pre-scaled coords if PC). 1024 x 256.
template<bool PC>
__global__ void k_scatter(const float* __restrict__ coords, const int* __restrict__ boff,
                          int* __restrict__ list, float4* __restrict__ pc4) {
    int t = threadIdx.x, bid = blockIdx.x, lane = t & 63, wv = t >> 6;
    const float4* c4 = (const float4*)coords + 768 * (size_t)bid + 3 * t;
    float4 a = c4[0], b = c4[1], c = c4[2];
    int base = bid * 1024 + t * 4;
    float xs[4] = {a.x, a.w, b.z, c.y};
    float ys[4] = {a.y, b.x, b.w, c.z};
    float zs[4] = {a.z, b.y, c.x, c.w};
    bool act[4];
#pragma unroll
    for (int j = 0; j < 4; ++j) act[j] = isact(xs[j], ys[j], zs[j]);
    int mine = (int)act[0] + (int)act[1] + (int)act[2] + (int)act[3];
    int incl = mine;
#pragma unroll
    for (int off = 1; off <= 32; off <<= 1) {
        int v = __shfl_up(incl, off, 64);
        if (lane >= off) incl += v;
    }
    __shared__ int wtot[4];
    if (lane == 63) wtot[wv] = incl;
    __syncthreads();
    int wexcl = 0;
#pragma unroll
    for (int k = 0; k < 4; ++k) wexcl += (k < wv) ? wtot[k] : 0;
    int pos = boff[bid] + wexcl + incl - mine;
#pragma unroll
    for (int j = 0; j < 4; ++j) {
        if (act[j]) {
            list[pos] = base + j;
            if (PC) {
                float4 p;
                p.x = fmaf(xs[j], 15.5f, 15.5f);
                p.y = fmaf(ys[j], 15.5f, 15.5f);
                p.z = fmaf(zs[j], 15.5f, 15.5f);
                p.w = 0.0f;
                pc4[pos] = p;
            }
            ++pos;
        }
    }
}

// K3 (tier B, MAIN): fused sample + MFMA MLP, one 64-pt tile per block.
// LDS aliased (19456 B). Sampling: 2 passes batched -> 12 global loads in
// flight before any fdot2 (2x memory-level parallelism vs serialized passes).
__global__ __launch_bounds__(256, 2)
void k_fused(const float4* __restrict__ pc4, const f16* __restrict__ dupl,
             const f16* __restrict__ w1h, const f16* __restrict__ w2h,
             const float* __restrict__ b1, const float* __restrict__ b2,
             const float* __restrict__ w3, const float* __restrict__ b3,
             const int* __restrict__ cnt, const int* __restrict__ list,
             float* __restrict__ out) {
    const int n = *cnt;
    const int tile = blockIdx.x;
    if (tile * 64 >= n) return;

    __shared__ __attribute__((aligned(16))) char smem[16384 + 3072];
    f16*   Fs   = (f16*)smem;              // [pt][c] swizzled; dies at af-load
    f16*   H1s  = (f16*)smem;              // [pt][neuron] swizzled; born after
    int4*  BsP  = (int4*)(smem + 16384);   // 64x3; dies after sampling
    float* outp = (float*)(smem + 16384);  // [4][64]; born at epilogue

    const int t   = threadIdx.x;
    const int wv  = t >> 6;
    const int l   = t & 63;
    const int l15 = l & 15;
    const int lg  = l >> 4;
    const int ptw = t >> 4;
    const int cq  = t & 15;

    const float b3v = b3[0];

    // ---------- phase 0: dot2 bilinear setup, once per (point, plane) ----------
    if ((t & 3) < 3) {
        int pt0 = t >> 2;
        int pl  = t & 3;
        int ic = imin(tile * 64 + pt0, n - 1);
        float4 c = pc4[ic];
        float pa = (pl == 1) ? c.y : c.x;
        float pb = (pl == 0) ? c.y : c.z;
        float fa = floorf(pa), fb = floorf(pb);
        int ia0 = (int)fa, ib0 = (int)fb;
        float wa1 = pa - fa, wa0 = 1.0f - wa1;
        float wb1 = pb - fb, wb0 = 1.0f - wb1;
        float va0 = (ia0 >= 0 && ia0 < 32) ? wa0 : 0.0f;
        float va1 = (ia0 + 1 >= 0 && ia0 + 1 < 32) ? wa1 : 0.0f;
        float vb0 = (ib0 >= 0 && ib0 < 32) ? wb0 : 0.0f;
        float vb1 = (ib0 + 1 >= 0 && ib0 + 1 < 32) ? wb1 : 0.0f;
        int xb = iclamp(ia0, 0, 31);
        float wx0 = (ia0 < 0) ? va1 : va0;
        float wx1 = (ia0 < 0) ? 0.0f : va1;
        int yb0 = iclamp(ib0, 0, 31), yb1 = iclamp(ib0 + 1, 0, 31);
        f16x2 p0; p0[0] = (f16)(wx0 * vb0); p0[1] = (f16)(wx1 * vb0);
        f16x2 p1; p1[0] = (f16)(wx0 * vb1); p1[1] = (f16)(wx1 * vb1);
        int o0 = (yb0 * 32 + xb) * 128;
        int o1 = (yb1 * 32 + xb) * 128;
        BsP[pt0 * 3 + pl] = make_int4(o0, o1,
                                      __builtin_bit_cast(int, p0),
                                      __builtin_bit_cast(int, p1));
    }
    __syncthreads();

    // ---------- sampling into Fs: 2x (2 passes, batched loads) ----------
    const f16* bch = dupl + cq * 8;
#pragma unroll
    for (int pp = 0; pp < 2; ++pp) {
        int ptA = (2 * pp) * 16 + ptw;
        int ptB = (2 * pp + 1) * 16 + ptw;
        int4 PA0 = BsP[ptA * 3 + 0], PA1 = BsP[ptA * 3 + 1], PA2 = BsP[ptA * 3 + 2];
        int4 PB0 = BsP[ptB * 3 + 0], PB1 = BsP[ptB * 3 + 1], PB2 = BsP[ptB * 3 + 2];
        // issue all 12 loads before any compute
        f16x8 A00 = *(const f16x8*)(bch + PA0.x);
        f16x8 A01 = *(const f16x8*)(bch + PA0.y);
        f16x8 A10 = *(const f16x8*)(bch + 131072 + PA1.x);
        f16x8 A11 = *(const f16x8*)(bch + 131072 + PA1.y);
        f16x8 A20 = *(const f16x8*)(bch + 262144 + PA2.x);
        f16x8 A21 = *(const f16x8*)(bch + 262144 + PA2.y);
        f16x8 B00 = *(const f16x8*)(bch + PB0.x);
        f16x8 B01 = *(const f16x8*)(bch + PB0.y);
        f16x8 B10 = *(const f16x8*)(bch + 131072 + PB1.x);
        f16x8 B11 = *(const f16x8*)(bch + 131072 + PB1.y);
        f16x8 B20 = *(const f16x8*)(bch + 262144 + PB2.x);
        f16x8 B21 = *(const f16x8*)(bch + 262144 + PB2.y);
        // pass A
        {
            float4 s0 = dot4p(A00, A01, PA0.z, PA0.w);
            float4 s1 = dot4p(A10, A11, PA1.z, PA1.w);
            float4 s2 = dot4p(A20, A21, PA2.z, PA2.w);
            float4 f;
            f.x = (s0.x * s1.x) * s2.x;
            f.y = (s0.y * s1.y) * s2.y;
            f.z = (s0.z * s1.z) * s2.z;
            f.w = (s0.w * s1.w) * s2.w;
            f16x4 pk;
            pk[0] = (f16)f.x; pk[1] = (f16)f.y; pk[2] = (f16)f.z; pk[3] = (f16)f.w;
            *(f16x4*)((char*)Fs + ptA * 128 + ((cq * 8) ^ ((ptA & 7) << 4))) = pk;
        }
        // pass B
        {
            float4 s0 = dot4p(B00, B01, PB0.z, PB0.w);
            float4 s1 = dot4p(B10, B11, PB1.z, PB1.w);
            float4 s2 = dot4p(B20, B21, PB2.z, PB2.w);
            float4 f;
            f.x = (s0.x * s1.x) * s2.x;
            f.y = (s0.y * s1.y) * s2.y;
            f.z = (s0.z * s1.z) * s2.z;
            f.w = (s0.w * s1.w) * s2.w;
            f16x4 pk;
            pk[0] = (f16)f.x; pk[1] = (f16)f.y; pk[2] = (f16)f.z; pk[3] = (f16)f.w;
            *(f16x4*)((char*)Fs + ptB * 128 + ((cq * 8) ^ ((ptB & 7) << 4))) = pk;
        }
    }
    __syncthreads();   // Fs ready (and all BsP reads done)

    // ---------- B-frags (features) from Fs ----------
    f16x8 af[4][2];
#pragma unroll
    for (int Mt = 0; Mt < 4; ++Mt) {
        int row = Mt * 16 + l15;
        const char* rb = (const char*)Fs + row * 128;
        int sw = (row & 7) << 4;
        af[Mt][0] = *(const f16x8*)(rb + ((lg * 16) ^ sw));
        af[Mt][1] = *(const f16x8*)(rb + ((64 + lg * 16) ^ sw));
    }

    // ---------- A-frags (weights) + per-lane bias/w3 quads (L1-hot) ----------
    f16x8 wf1[2][2];
    f16x8 wf2[2][4];
    f32x4 b1q[2], b2q[2], w3q[2];
#pragma unroll
    for (int ntl = 0; ntl < 2; ++ntl) {
        int nrow = (wv * 2 + ntl) * 16 + l15;
        wf1[ntl][0] = *(const f16x8*)(w1h + nrow * 64 + lg * 8);
        wf1[ntl][1] = *(const f16x8*)(w1h + nrow * 64 + 32 + lg * 8);
#pragma unroll
        for (int ks = 0; ks < 4; ++ks)
            wf2[ntl][ks] = *(const f16x8*)(w2h + nrow * 128 + ks * 32 + lg * 8);
        int nb = (wv * 2 + ntl) * 16 + lg * 4;
        b1q[ntl] = *(const f32x4*)(b1 + nb);
        b2q[ntl] = *(const f32x4*)(b2 + nb);
        w3q[ntl] = *(const f32x4*)(w3 + nb);
    }
    __syncthreads();   // all waves done reading Fs -> H1s may overwrite

    // ---------- layer 1: C1[neuron][pt] ----------
    f32x4 acc[2][4];
#pragma unroll
    for (int ntl = 0; ntl < 2; ++ntl)
#pragma unroll
        for (int Mt = 0; Mt < 4; ++Mt) acc[ntl][Mt] = b1q[ntl];
    __builtin_amdgcn_s_setprio(1);
#pragma unroll
    for (int Mt = 0; Mt < 4; ++Mt) {
#pragma unroll
        for (int ntl = 0; ntl < 2; ++ntl) {
            acc[ntl][Mt] = __builtin_amdgcn_mfma_f32_16x16x32_f16(wf1[ntl][0], af[Mt][0], acc[ntl][Mt], 0, 0, 0);
            acc[ntl][Mt] = __builtin_amdgcn_mfma_f32_16x16x32_f16(wf1[ntl][1], af[Mt][1], acc[ntl][Mt], 0, 0, 0);
        }
    }
    __builtin_amdgcn_s_setprio(0);

    // ---------- H1 -> LDS (overlays Fs) ----------
#pragma unroll
    for (int ntl = 0; ntl < 2; ++ntl) {
#pragma unroll
        for (int Mt = 0; Mt < 4; ++Mt) {
            int pt = Mt * 16 + l15;
            int off = (((wv * 2 + ntl) * 32 + lg * 8) ^ ((pt & 7) << 4));
            f16x4 h;
            h[0] = (f16)fmaxf(acc[ntl][Mt][0], 0.0f);
            h[1] = (f16)fmaxf(acc[ntl][Mt][1], 0.0f);
            h[2] = (f16)fmaxf(acc[ntl][Mt][2], 0.0f);
            h[3] = (f16)fmaxf(acc[ntl][Mt][3], 0.0f);
            *(f16x4*)((char*)H1s + pt * 256 + off) = h;
        }
    }
    __syncthreads();   // H1s ready

    // ---------- layer 2: C2[neuron][pt] ----------
    f32x4 acc2[2][4];
#pragma unroll
    for (int ntl = 0; ntl < 2; ++ntl)
#pragma unroll
        for (int Mt = 0; Mt < 4; ++Mt) acc2[ntl][Mt] = b2q[ntl];
#pragma unroll
    for (int Mt = 0; Mt < 4; ++Mt) {
        int row = Mt * 16 + l15;
        const char* rb = (const char*)H1s + row * 256;
        int sw = (row & 7) << 4;
        f16x8 a0 = *(const f16x8*)(rb + ((lg * 16) ^ sw));
        f16x8 a1 = *(const f16x8*)(rb + ((64 + lg * 16) ^ sw));
        f16x8 a2 = *(const f16x8*)(rb + ((128 + lg * 16) ^ sw));
        f16x8 a3 = *(const f16x8*)(rb + ((192 + lg * 16) ^ sw));
        __builtin_amdgcn_s_setprio(1);
#pragma unroll
        for (int ntl = 0; ntl < 2; ++ntl) {
            acc2[ntl][Mt] = __builtin_amdgcn_mfma_f32_16x16x32_f16(wf2[ntl][0], a0, acc2[ntl][Mt], 0, 0, 0);
            acc2[ntl][Mt] = __builtin_amdgcn_mfma_f32_16x16x32_f16(wf2[ntl][1], a1, acc2[ntl][Mt], 0, 0, 0);
            acc2[ntl][Mt] = __builtin_amdgcn_mfma_f32_16x16x32_f16(wf2[ntl][2], a2, acc2[ntl][Mt], 0, 0, 0);
            acc2[ntl][Mt] = __builtin_amdgcn_mfma_f32_16x16x32_f16(wf2[ntl][3], a3, acc2[ntl][Mt], 0, 0, 0);
        }
        __builtin_amdgcn_s_setprio(0);
    }

    // ---------- layer 3: lane-local over 8 neurons + 2 shuffles ----------
#pragma unroll
    for (int Mt = 0; Mt < 4; ++Mt) {
        float s = 0.0f;
#pragma unroll
        for (int ntl = 0; ntl < 2; ++ntl)
#pragma unroll
            for (int r = 0; r < 4; ++r)
                s = fmaf(fmaxf(acc2[ntl][Mt][r], 0.0f), w3q[ntl][r], s);
        s += __shfl_xor(s, 16, 64);
        s += __shfl_xor(s, 32, 64);
        if (lg == 0) outp[wv * 64 + Mt * 16 + l15] = s;
    }
    __syncthreads();   // outp ready
    if (t < 64) {
        int gi = tile * 64 + t;
        if (gi < n) {
            float s = outp[0 * 64 + t] + outp[1 * 64 + t] +
                      outp[2 * 64 + t] + outp[3 * 64 + t] + b3v;
            out[list[gi]] = s;
        }
    }
}

// K3 (tier C): fused via list, f32 planes. 16384 x 256.
__global__ __launch_bounds__(256, 2)
void k_mlp(const float* __restrict__ coords, const float* __restrict__ planes,
           const f16* __restrict__ w1h, const f16* __restrict__ w2h,
           const float* __restrict__ b1, const float* __restrict__ b2,
           const float* __restrict__ w3, const float* __restrict__ b3,
           const int* __restrict__ cnt, const int* __restrict__ list,
           float* __restrict__ out) {
    const int n = *cnt;
    const int tile = blockIdx.x;
    if (tile * 64 >= n) return;

    __shared__ __attribute__((aligned(16))) f16 Fs[64 * 64];
    __shared__ __attribute__((aligned(16))) f16 H1s[64 * 128];
    __shared__ float outp[4][64];

    const int t   = threadIdx.x;
    const int wv  = t >> 6;
    const int l   = t & 63;
    const int l15 = l & 15;
    const int lg  = l >> 4;

    const float* pl0 = planes;
    const float* pl1 = planes + 65536;
    const float* pl2 = planes + 131072;

    f16x8 wf1[2][2];
    f16x8 wf2[2][4];
    float b1v[2], b2v[2], w3v[2];
#pragma unroll
    for (int ntl = 0; ntl < 2; ++ntl) {
        int nrow = (wv * 2 + ntl) * 16 + l15;
#pragma unroll
        for (int ks = 0; ks < 2; ++ks)
            wf1[ntl][ks] = *(const f16x8*)(w1h + nrow * 64 + ks * 32 + lg * 8);
#pragma unroll
        for (int ks = 0; ks < 4; ++ks)
            wf2[ntl][ks] = *(const f16x8*)(w2h + nrow * 128 + ks * 32 + lg * 8);
        b1v[ntl] = b1[nrow];
        b2v[ntl] = b2[nrow];
        w3v[ntl] = w3[nrow];
    }
    const float b3v = b3[0];

    {
        int pt = t >> 2, c0 = (t & 3) * 16;
        int ic = imin(tile * 64 + pt, n - 1);
        int i = list[ic];
        float px = fmaf(coords[3 * i + 0], 15.5f, 15.5f);
        float py = fmaf(coords[3 * i + 1], 15.5f, 15.5f);
        float pz = fmaf(coords[3 * i + 2], 15.5f, 15.5f);
        float feat[16];
        samp16(pl0, px, py, c0, feat, false);
        samp16(pl1, py, pz, c0, feat, true);
        samp16(pl2, px, pz, c0, feat, true);
        int sw = (pt & 7) << 4;
        char* Fb = (char*)Fs + pt * 128;
        f16x8 pk;
#pragma unroll
        for (int j = 0; j < 8; ++j) pk[j] = (f16)feat[j];
        *(f16x8*)(Fb + ((c0 * 2) ^ sw)) = pk;
#pragma unroll
        for (int j = 0; j < 8; ++j) pk[j] = (f16)feat[8 + j];
        *(f16x8*)(Fb + ((c0 * 2 + 16) ^ sw)) = pk;
    }
    __syncthreads();

    f32x4 acc[2][4];
#pragma unroll
    for (int ntl = 0; ntl < 2; ++ntl) {
        f32x4 ini = {b1v[ntl], b1v[ntl], b1v[ntl], b1v[ntl]};
#pragma unroll
        for (int Mt = 0; Mt < 4; ++Mt) acc[ntl][Mt] = ini;
    }
#pragma unroll
    for (int Mt = 0; Mt < 4; ++Mt) {
        int row = Mt * 16 + l15;
        const char* rb = (const char*)Fs + row * 128;
        int sw = (row & 7) << 4;
        f16x8 a0 = *(const f16x8*)(rb + ((lg * 16) ^ sw));
        f16x8 a1 = *(const f16x8*)(rb + ((64 + lg * 16) ^ sw));
#pragma unroll
        for (int ntl = 0; ntl < 2; ++ntl) {
            acc[ntl][Mt] = __builtin_amdgcn_mfma_f32_16x16x32_f16(a0, wf1[ntl][0], acc[ntl][Mt], 0, 0, 0);
            acc[ntl][Mt] = __builtin_amdgcn_mfma_f32_16x16x32_f16(a1, wf1[ntl][1], acc[ntl][Mt], 0, 0, 0);
        }
    }
#pragma unroll
    for (int ntl = 0; ntl < 2; ++ntl) {
        int ncol = (wv * 2 + ntl) * 16 + l15;
#pragma unroll
        for (int Mt = 0; Mt < 4; ++Mt) {
#pragma unroll
            for (int r = 0; r < 4; ++r) {
                int prow = Mt * 16 + lg * 4 + r;
                float v = fmaxf(acc[ntl][Mt][r], 0.0f);
                *(f16*)((char*)H1s + prow * 256 + ((ncol * 2) ^ ((prow & 7) << 4))) = (f16)v;
            }
        }
    }
    __syncthreads();

    f32x4 acc2[2][4];
#pragma unroll
    for (int ntl = 0; ntl < 2; ++ntl) {
        f32x4 ini = {b2v[ntl], b2v[ntl], b2v[ntl], b2v[ntl]};
#pragma unroll
        for (int Mt = 0; Mt < 4; ++Mt) acc2[ntl][Mt] = ini;
    }
#pragma unroll
    for (int Mt = 0; Mt < 4; ++Mt) {
        int row = Mt * 16 + l15;
        const char* rb = (const char*)H1s + row * 256;
        int sw = (row & 7) << 4;
        f16x8 a0 = *(const f16x8*)(rb + ((lg * 16) ^ sw));
        f16x8 a1 = *(const f16x8*)(rb + ((64 + lg * 16) ^ sw));
        f16x8 a2 = *(const f16x8*)(rb + ((128 + lg * 16) ^ sw));
        f16x8 a3 = *(const f16x8*)(rb + ((192 + lg * 16) ^ sw));
#pragma unroll
        for (int ntl = 0; ntl < 2; ++ntl) {
            acc2[ntl][Mt] = __builtin_amdgcn_mfma_f32_16x16x32_f16(a0, wf2[ntl][0], acc2[ntl][Mt], 0, 0, 0);
            acc2[ntl][Mt] = __builtin_amdgcn_mfma_f32_16x16x32_f16(a1, wf2[ntl][1], acc2[ntl][Mt], 0, 0, 0);
            acc2[ntl][Mt] = __builtin_amdgcn_mfma_f32_16x16x32_f16(a2, wf2[ntl][2], acc2[ntl][Mt], 0, 0, 0);
            acc2[ntl][Mt] = __builtin_amdgcn_mfma_f32_16x16x32_f16(a3, wf2[ntl][3], acc2[ntl][Mt], 0, 0, 0);
        }
    }

    float part[4][4];
#pragma unroll
    for (int Mt = 0; Mt < 4; ++Mt)
#pragma unroll
        for (int r = 0; r < 4; ++r)
            part[Mt][r] = fmaxf(acc2[0][Mt][r], 0.0f) * w3v[0] +
                          fmaxf(acc2[1][Mt][r], 0.0f) * w3v[1];
#pragma unroll
    for (int off = 1; off <= 8; off <<= 1) {
#pragma unroll
        for (int Mt = 0; Mt < 4; ++Mt)
#pragma unroll
            for (int r = 0; r < 4; ++r)
                part[Mt][r] += __shfl_xor(part[Mt][r], off, 64);
    }
    if (l15 == 0) {
#pragma unroll
        for (int Mt = 0; Mt < 4; ++Mt)
#pragma unroll
            for (int r = 0; r < 4; ++r)
                outp[wv][Mt * 16 + lg * 4 + r] = part[Mt][r];
    }
    __syncthreads();
    if (t < 64) {
        int gi = tile * 64 + t;
        if (gi < n) {
            float s = outp[0][t] + outp[1][t] + outp[2][t] + outp[3][t] + b3v;
            out[list[gi]] = s;
        }
    }
}

// Fallback (no workspace): per-thread f32 MLP over all points.
__global__ void k_fallback(const float* __restrict__ coords,
                           const float* __restrict__ p0, const float* __restrict__ p1,
                           const float* __restrict__ p2,
                           const float* __restrict__ w1, const float* __restrict__ b1,
                           const float* __restrict__ w2, const float* __restrict__ b2,
                           const float* __restrict__ w3, const float* __restrict__ b3,
                           float* __restrict__ out) {
    int i = blockIdx.x * 256 + threadIdx.x;
    if (i >= MPTS) return;
    float x = coords[3 * i + 0], y = coords[3 * i + 1], z = coords[3 * i + 2];
    float px = fmaf(x, 15.5f, 15.5f);
    float py = fmaf(y, 15.5f, 15.5f);
    float pz = fmaf(z, 15.5f, 15.5f);
    float feat[64];
    const float* pls[3] = {p0, p1, p2};
    float pa[3] = {px, py, px}, pb[3] = {py, pz, pz};
    for (int pidx = 0; pidx < 3; ++pidx) {
        float paf = pa[pidx], pbf = pb[pidx];
        float fa = floorf(paf), fb = floorf(pbf);
        int ia0 = (int)fa, ib0 = (int)fb, ia1 = ia0 + 1, ib1 = ib0 + 1;
        float wa1 = paf - fa, wa0 = 1.0f - wa1, wb1 = pbf - fb, wb0 = 1.0f - wb1;
        float va0 = (ia0 >= 0 && ia0 < 32) ? wa0 : 0.0f;
        float va1 = (ia1 >= 0 && ia1 < 32) ? wa1 : 0.0f;
        float vb0 = (ib0 >= 0 && ib0 < 32) ? wb0 : 0.0f;
        float vb1 = (ib1 >= 0 && ib1 < 32) ? wb1 : 0.0f;
        int ca0 = iclamp(ia0, 0, 31), ca1 = iclamp(ia1, 0, 31);
        int cb0 = iclamp(ib0, 0, 31), cb1 = iclamp(ib1, 0, 31);
        float w00 = va0 * vb0, w01 = va1 * vb0, w10 = va0 * vb1, w11 = va1 * vb1;
        int o00 = cb0 * 32 + ca0, o01 = cb0 * 32 + ca1;
        int o10 = cb1 * 32 + ca0, o11 = cb1 * 32 + ca1;
        const float* pl = pls[pidx];
        for (int c = 0; c < 64; ++c) {
            const float* pc = pl + c * 1024;
            float v = fmaf(w00, pc[o00], fmaf(w01, pc[o01],
                      fmaf(w10, pc[o10], w11 * pc[o11])));
            if (pidx == 0) feat[c] = v; else feat[c] *= v;
        }
    }
    float oa = b3[0];
    for (int half = 0; half < 2; ++half) {
        float h2h[64];
        for (int p = 0; p < 64; ++p) h2h[p] = b2[half * 64 + p];
        for (int o = 0; o < 128; ++o) {
            float a = b1[o];
            for (int c = 0; c < 64; ++c) a = fmaf(feat[c], w1[o * 64 + c], a);
            float r = fmaxf(a, 0.0f);
            for (int p = 0; p < 64; ++p) h2h[p] = fmaf(r, w2[(half * 64 + p) * 128 + o], h2h[p]);
        }
        for (int p = 0; p < 64; ++p) oa = fmaf(fmaxf(h2h[p], 0.0f), w3[half * 64 + p], oa);
    }
    out[i] = oa;
}

extern "C" void kernel_launch(void* const* d_in, const int* in_sizes, int n_in,
                              void* d_out, int out_size, void* d_ws, size_t ws_size,
                              hipStream_t stream) {
    const float* coords = (const float*)d_in[0];
    const float* pxy    = (const float*)d_in[1];
    const float* pyz    = (const float*)d_in[2];
    const float* pxz    = (const float*)d_in[3];
    const float* w1     = (const float*)d_in[4];
    const float* b1     = (const float*)d_in[5];
    const float* w2     = (const float*)d_in[6];
    const float* b2     = (const float*)d_in[7];
    const float* w3     = (const float*)d_in[8];
    const float* b3     = (const float*)d_in[9];
    float* out = (float*)d_out;

    if (ws_size >= WS_LIST) {
        float*  zout   = (float*)((char*)d_ws + OFF_Z);
        int*    cnt    = (int*)((char*)d_ws + OFF_CNT);
        float*  planes = (float*)((char*)d_ws + OFF_PL);
        f16*    dupl   = (f16*)((char*)d_ws + OFF_PLD);
        f16*    w1h    = (f16*)((char*)d_ws + OFF_W1H);
        f16*    w2h    = (f16*)((char*)d_ws + OFF_W2H);
        int*    bcnt   = (int*)((char*)d_ws + OFF_BCNT);
        int*    boff   = (int*)((char*)d_ws + OFF_BOFF);
        int*    list   = (int*)((char*)d_ws + OFF_LIST);
        float4* pc4    = (float4*)((char*)d_ws + OFF_PC);
        const bool pc  = (ws_size >= WS_PC);

        k_prep<<<865, 256, 0, stream>>>(pxy, pyz, pxz, w1, w2, b1, b2, w3, b3,
                                        planes, dupl, w1h, w2h, zout, pc ? 0 : 1);
        k_count<<<1024, 256, 0, stream>>>(coords, zout, bcnt, out);
        k_scan<<<1, 1024, 0, stream>>>(bcnt, boff, cnt);

        if (pc) {
            k_scatter<true><<<1024, 256, 0, stream>>>(coords, boff, list, pc4);
            k_fused<<<16384, 256, 0, stream>>>(pc4, dupl, w1h, w2h,
                                               b1, b2, w3, b3, cnt, list, out);
        } else {
            k_scatter<false><<<1024, 256, 0, stream>>>(coords, boff, list, nullptr);
            k_mlp<<<16384, 256, 0, stream>>>(coords, planes, w1h, w2h,
                                             b1, b2, w3, b3, cnt, list, out);
        }
    } else {
        k_fallback<<<4096, 256, 0, stream>>>(coords, pxy, pyz, pxz,
                                             w1, b1, w2, b2, w3, b3, out);
    }
}